// Round 5
// baseline (122.794 us; speedup 1.0000x reference)
//
#include <hip/hip_runtime.h>
#include <hip/hip_cooperative_groups.h>
#include <math.h>

namespace cg = cooperative_groups;

#define BB 64
#define ZZ 8
#define UU 8
#define PP 128
#define XX 64
#define HH 512

typedef float f32x4 __attribute__((ext_vector_type(4)));
typedef float f32x2 __attribute__((ext_vector_type(2)));

__device__ __forceinline__ float elu(float v) {
    return v > 0.f ? v : (expf(v) - 1.f);
}

// ---------------------------------------------------------------------------
// One col-chunk of a GEMV layer: out[c0 .. c0+NCOLS) = act(hs @ W + bias).
// hs = full input row staged in LDS (K floats). 256 threads split as
// GROUPS=NCOLS/4 f32x4 column groups x SLICES=256/GROUPS K-slices.
// red is an LDS partial buffer with +1 f32x4 padding per slice row to avoid
// the 32-way bank conflict in the final strided reduce.
// ---------------------------------------------------------------------------
template<int K, int NCOLS, bool ELU>
__device__ __forceinline__ void chunk_gemv(
    const float* __restrict__ hs, const float* __restrict__ W,
    const float* __restrict__ bias, float* __restrict__ outRow,
    int N, int c0, int tid, f32x4* __restrict__ red) {
    constexpr int GROUPS = NCOLS / 4;
    constexpr int SLICES = 256 / GROUPS;
    constexpr int KPER   = K / SLICES;
    const int g    = tid % GROUPS;
    const int ks   = tid / GROUPS;
    const int kBeg = ks * KPER;
    const float* Wp = W + (size_t)kBeg * N + c0 + g * 4;

    f32x4 acc = {0.f, 0.f, 0.f, 0.f};
    #pragma unroll 8
    for (int k = 0; k < KPER; ++k) {
        const f32x4 w = *(const f32x4*)(Wp + (size_t)k * N);
        const float s = hs[kBeg + k];
        acc.x = fmaf(s, w.x, acc.x);
        acc.y = fmaf(s, w.y, acc.y);
        acc.z = fmaf(s, w.z, acc.z);
        acc.w = fmaf(s, w.w, acc.w);
    }
    red[ks * (GROUPS + 1) + g] = acc;
    __syncthreads();

    if (tid < GROUPS) {
        f32x4 a = red[tid];
        #pragma unroll
        for (int s2 = 1; s2 < SLICES; ++s2) {
            const f32x4 b = red[s2 * (GROUPS + 1) + tid];
            a.x += b.x; a.y += b.y; a.z += b.z; a.w += b.w;
        }
        const f32x4 bb = *(const f32x4*)(bias + c0 + tid * 4);
        a.x += bb.x; a.y += bb.y; a.z += bb.z; a.w += bb.w;
        if (ELU) { a.x = elu(a.x); a.y = elu(a.y); a.z = elu(a.z); a.w = elu(a.w); }
        *(f32x4*)(outRow + c0 + tid * 4) = a;
    }
    __syncthreads();   // red/hs safe for reuse
}

// ---------------------------------------------------------------------------
// Whole MLP in ONE cooperative dispatch. grid = 256 blocks = 64 rows x 4
// col-chunks, 256 threads. Phase A: full h1 row in LDS (W1 is 128 KB,
// L2-shared; redundant per block is ~free), then h2 chunk. grid.sync.
// Phase B: h3 chunk. grid.sync. Phase C: phi 32-col chunk.
// ---------------------------------------------------------------------------
__global__ __launch_bounds__(256) void mlp_coop(
    const float* __restrict__ x,
    const float* __restrict__ W1, const float* __restrict__ b1,
    const float* __restrict__ W2, const float* __restrict__ b2,
    const float* __restrict__ W3, const float* __restrict__ b3,
    const float* __restrict__ W4, const float* __restrict__ b4,
    float* __restrict__ h2buf, float* __restrict__ h3buf,
    float* __restrict__ phi) {
    cg::grid_group grid = cg::this_grid();

    __shared__ __align__(16) float xs[XX];
    __shared__ __align__(16) float hs[HH];
    __shared__ __align__(16) f32x4 red[288];   // fits 8x33 and 32x9 padded

    const int tid = threadIdx.x;
    const int r   = blockIdx.x >> 2;   // row 0..63
    const int c   = blockIdx.x & 3;    // col-chunk 0..3

    // ---- Phase A: h1 full row (K=64) into LDS ----
    if (tid < XX) xs[tid] = x[(size_t)r * XX + tid];
    __syncthreads();
    {
        const f32x2* W = (const f32x2*)W1;   // [XX][HH/2]
        f32x2 a0 = {0.f, 0.f}, a1 = {0.f, 0.f};
        #pragma unroll 8
        for (int k = 0; k < XX; k += 2) {
            const f32x2 w0 = W[(k + 0) * (HH / 2) + tid];
            const f32x2 w1 = W[(k + 1) * (HH / 2) + tid];
            const float s0 = xs[k + 0], s1 = xs[k + 1];
            a0.x = fmaf(s0, w0.x, a0.x); a0.y = fmaf(s0, w0.y, a0.y);
            a1.x = fmaf(s1, w1.x, a1.x); a1.y = fmaf(s1, w1.y, a1.y);
        }
        const f32x2 bb = ((const f32x2*)b1)[tid];
        hs[2 * tid + 0] = elu(a0.x + a1.x + bb.x);
        hs[2 * tid + 1] = elu(a0.y + a1.y + bb.y);
    }
    __syncthreads();

    // ---- h2 chunk (128 cols) ----
    chunk_gemv<HH, 128, true>(hs, W2, b2, h2buf + (size_t)r * HH, HH, c * 128, tid, red);
    grid.sync();

    // ---- Phase B: h3 chunk ----
    ((f32x2*)hs)[tid] = ((const f32x2*)(h2buf + (size_t)r * HH))[tid];
    __syncthreads();
    chunk_gemv<HH, 128, true>(hs, W3, b3, h3buf + (size_t)r * HH, HH, c * 128, tid, red);
    grid.sync();

    // ---- Phase C: phi chunk (32 cols) ----
    ((f32x2*)hs)[tid] = ((const f32x2*)(h3buf + (size_t)r * HH))[tid];
    __syncthreads();
    chunk_gemv<HH, 32, false>(hs, W4, b4, phi + (size_t)r * PP, PP, c * 32, tid, red);
}

// ---------------------------------------------------------------------------
// Per-(b,z,u) bilinear forms over Linv (128x128 fp32 each):
//   mu  = sum_{i,j} phi_b[i] * L[i,j] * Qv[j]
//   cov = exp(logSigEps[u]) * (1 + sum_{i,j} phi_b[i] * L[i,j] * phi_b[j])
// One block (256 threads) per matrix; 16 f32x4 loads/thread, coalesced.
// q/p fragments are iteration-invariant -> hoisted to registers.
// ---------------------------------------------------------------------------
__global__ __launch_bounds__(256) void bilinear_kernel(
    const float* __restrict__ Linv, const float* __restrict__ Q,
    const float* __restrict__ phi, const float* __restrict__ logSigEps,
    float* __restrict__ out_mu, float* __restrict__ out_cov) {
    __shared__ __align__(16) float Ps[PP];
    __shared__ __align__(16) float Qs[PP];
    __shared__ float red[8];

    const int bzu = blockIdx.x;        // b*64 + z*8 + u
    const int b   = bzu >> 6;
    const int u   = bzu & 7;
    const int tid = threadIdx.x;

    if (tid < 32)      ((f32x4*)Ps)[tid]      = ((const f32x4*)(phi + (size_t)b * PP))[tid];
    else if (tid < 64) ((f32x4*)Qs)[tid - 32] = ((const f32x4*)(Q + (size_t)bzu * PP))[tid - 32];
    __syncthreads();

    const int j0 = (tid & 31) << 2;            // constant across iterations
    const f32x4 q = *(const f32x4*)(Qs + j0);
    const f32x4 p = *(const f32x4*)(Ps + j0);

    const f32x4* L4 = (const f32x4*)(Linv + (size_t)bzu * (PP * PP));
    float accM = 0.f, accS = 0.f;
    #pragma unroll
    for (int it = 0; it < 16; ++it) {
        const int f = it * 256 + tid;          // float4 index within the matrix
        const f32x4 L = L4[f];
        const float pi = Ps[f >> 5];           // LDS broadcast (32 lanes/addr)
        const float sm = L.x * q.x + L.y * q.y + L.z * q.z + L.w * q.w;
        const float sp = L.x * p.x + L.y * p.y + L.z * p.z + L.w * p.w;
        accM = fmaf(pi, sm, accM);
        accS = fmaf(pi, sp, accS);
    }

    for (int off = 32; off; off >>= 1) {
        accM += __shfl_down(accM, off, 64);
        accS += __shfl_down(accS, off, 64);
    }
    const int wid = tid >> 6;
    if ((tid & 63) == 0) { red[wid] = accM; red[4 + wid] = accS; }
    __syncthreads();
    if (tid == 0) {
        const float m = (red[0] + red[1]) + (red[2] + red[3]);
        const float s = (red[4] + red[5]) + (red[6] + red[7]);
        out_mu[bzu]  = m;
        out_cov[bzu] = expf(logSigEps[u]) * (1.f + s);
    }
}

extern "C" void kernel_launch(void* const* d_in, const int* in_sizes, int n_in,
                              void* d_out, int out_size, void* d_ws, size_t ws_size,
                              hipStream_t stream) {
    const float* x         = (const float*)d_in[0];
    const float* Linv      = (const float*)d_in[1];
    const float* Q         = (const float*)d_in[2];
    const float* W1        = (const float*)d_in[3];
    const float* b1        = (const float*)d_in[4];
    const float* W2        = (const float*)d_in[5];
    const float* b2        = (const float*)d_in[6];
    const float* W3        = (const float*)d_in[7];
    const float* b3        = (const float*)d_in[8];
    const float* W4        = (const float*)d_in[9];
    const float* b4        = (const float*)d_in[10];
    const float* logSigEps = (const float*)d_in[11];

    float* ws  = (float*)d_ws;
    float* h2  = ws;                 // 64*512
    float* h3  = ws + BB * HH;       // 64*512
    float* phi = ws + 2 * BB * HH;   // 64*128

    void* args[] = {(void*)&x, (void*)&W1, (void*)&b1, (void*)&W2, (void*)&b2,
                    (void*)&W3, (void*)&b3, (void*)&W4, (void*)&b4,
                    (void*)&h2, (void*)&h3, (void*)&phi};
    hipLaunchCooperativeKernel(reinterpret_cast<void*>(mlp_coop),
                               dim3(BB * 4), dim3(256), args, 0, stream);

    float* out_mu  = (float*)d_out;          // (B,Z,U,1) = 4096 floats
    float* out_cov = out_mu + BB * ZZ * UU;  // (B,Z,U)   = 4096 floats

    bilinear_kernel<<<BB * ZZ * UU, 256, 0, stream>>>(Linv, Q, phi, logSigEps,
                                                      out_mu, out_cov);
}

// Round 6
// 75.446 us; speedup vs baseline: 1.6276x; 1.6276x over previous
//
#include <hip/hip_runtime.h>
#include <math.h>

#define BB 64
#define ZZ 8
#define UU 8
#define PP 128
#define XX 64
#define HH 512

typedef float f32x4 __attribute__((ext_vector_type(4)));
typedef float f32x2 __attribute__((ext_vector_type(2)));

__device__ __forceinline__ float elu(float v) {
    return v > 0.f ? v : (expf(v) - 1.f);
}

// ---------------------------------------------------------------------------
// One col-chunk of a GEMV layer: out[c0 .. c0+128) = act(hs @ W + bias).
// hs = full input row staged in LDS (K floats). 256 threads = 32 f32x4
// column groups x 8 K-slices. red padded (+1 f32x4 per slice row).
// ---------------------------------------------------------------------------
template<int K, bool ELU>
__device__ __forceinline__ void chunk_gemv(
    const float* __restrict__ hs, const float* __restrict__ W,
    const float* __restrict__ bias, float* __restrict__ outRow,
    int N, int c0, int tid, f32x4* __restrict__ red) {
    constexpr int KPER = K / 8;
    const int g    = tid & 31;
    const int ks   = tid >> 5;
    const int kBeg = ks * KPER;
    const float* Wp = W + (size_t)kBeg * N + c0 + g * 4;

    f32x4 acc = {0.f, 0.f, 0.f, 0.f};
    #pragma unroll 8
    for (int k = 0; k < KPER; ++k) {
        const f32x4 w = *(const f32x4*)(Wp + (size_t)k * N);
        const float s = hs[kBeg + k];
        acc.x = fmaf(s, w.x, acc.x);
        acc.y = fmaf(s, w.y, acc.y);
        acc.z = fmaf(s, w.z, acc.z);
        acc.w = fmaf(s, w.w, acc.w);
    }
    red[ks * 33 + g] = acc;
    __syncthreads();

    if (tid < 32) {
        f32x4 a = red[tid];
        #pragma unroll
        for (int s2 = 1; s2 < 8; ++s2) {
            const f32x4 b = red[s2 * 33 + tid];
            a.x += b.x; a.y += b.y; a.z += b.z; a.w += b.w;
        }
        const f32x4 bb = *(const f32x4*)(bias + c0 + tid * 4);
        a.x += bb.x; a.y += bb.y; a.z += bb.z; a.w += bb.w;
        if (ELU) { a.x = elu(a.x); a.y = elu(a.y); a.z = elu(a.z); a.w = elu(a.w); }
        *(f32x4*)(outRow + c0 + tid * 4) = a;
    }
}

// ---------------------------------------------------------------------------
// Layers 1+2 fused: grid (4, 64). Each block recomputes the full h1 row
// (W1 is only 128 KB, L2-shared across the 4 col-chunks -> ~free), then
// produces its 128-col chunk of h2. No cross-block dependency.
// ---------------------------------------------------------------------------
__global__ __launch_bounds__(256) void l12_kernel(
    const float* __restrict__ x,
    const float* __restrict__ W1, const float* __restrict__ b1,
    const float* __restrict__ W2, const float* __restrict__ b2,
    float* __restrict__ h2buf) {
    __shared__ __align__(16) float xs[XX];
    __shared__ __align__(16) float hs[HH];
    __shared__ __align__(16) f32x4 red[8 * 33];

    const int tid = threadIdx.x;
    const int r   = blockIdx.y;
    const int c0  = blockIdx.x * 128;

    if (tid < XX) xs[tid] = x[(size_t)r * XX + tid];
    __syncthreads();

    {   // h1 full row: thread tid -> cols 2tid, 2tid+1
        const f32x2* W = (const f32x2*)W1;   // [XX][HH/2]
        f32x2 a0 = {0.f, 0.f}, a1 = {0.f, 0.f};
        #pragma unroll 8
        for (int k = 0; k < XX; k += 2) {
            const f32x2 w0 = W[(k + 0) * (HH / 2) + tid];
            const f32x2 w1 = W[(k + 1) * (HH / 2) + tid];
            const float s0 = xs[k + 0], s1 = xs[k + 1];
            a0.x = fmaf(s0, w0.x, a0.x); a0.y = fmaf(s0, w0.y, a0.y);
            a1.x = fmaf(s1, w1.x, a1.x); a1.y = fmaf(s1, w1.y, a1.y);
        }
        const f32x2 bb = ((const f32x2*)b1)[tid];
        hs[2 * tid + 0] = elu(a0.x + a1.x + bb.x);
        hs[2 * tid + 1] = elu(a0.y + a1.y + bb.y);
    }
    __syncthreads();

    chunk_gemv<HH, true>(hs, W2, b2, h2buf + (size_t)r * HH, HH, c0, tid, red);
}

// ---------------------------------------------------------------------------
// Layer 3: grid (4, 64). Stage h2 row, produce 128-col chunk of h3.
// ---------------------------------------------------------------------------
__global__ __launch_bounds__(256) void l3_kernel(
    const float* __restrict__ h2buf,
    const float* __restrict__ W3, const float* __restrict__ b3,
    float* __restrict__ h3buf) {
    __shared__ __align__(16) float hs[HH];
    __shared__ __align__(16) f32x4 red[8 * 33];

    const int tid = threadIdx.x;
    const int r   = blockIdx.y;
    const int c0  = blockIdx.x * 128;

    ((f32x2*)hs)[tid] = ((const f32x2*)(h2buf + (size_t)r * HH))[tid];
    __syncthreads();

    chunk_gemv<HH, true>(hs, W3, b3, h3buf + (size_t)r * HH, HH, c0, tid, red);
}

// ---------------------------------------------------------------------------
// Bilinear + fused layer 4. One block per (b,z,u) matrix.
// Prologue: phi row = h3_row @ W4 + b4 (W4 256 KB, L2-resident; redundant
// per block but hidden under the HBM stream -- VALUBusy was 5%).
// Main loop: 16 coalesced f32x4 loads/thread over the 128x128 matrix;
// q/p fragments iteration-invariant in registers; phi[i] via LDS broadcast.
// ---------------------------------------------------------------------------
__global__ __launch_bounds__(256) void bilinear_phi_kernel(
    const float* __restrict__ Linv, const float* __restrict__ Q,
    const float* __restrict__ h3buf,
    const float* __restrict__ W4, const float* __restrict__ b4,
    const float* __restrict__ logSigEps,
    float* __restrict__ out_mu, float* __restrict__ out_cov) {
    __shared__ __align__(16) float hs[HH];
    __shared__ __align__(16) float Ps[PP];
    __shared__ __align__(16) float Qs[PP];
    __shared__ __align__(16) f32x4 red4[8 * 33];
    __shared__ float red[8];

    const int bzu = blockIdx.x;        // b*64 + z*8 + u
    const int b   = bzu >> 6;
    const int u   = bzu & 7;
    const int tid = threadIdx.x;

    if (tid < 128)      ((f32x4*)hs)[tid]       = ((const f32x4*)(h3buf + (size_t)b * HH))[tid];
    else if (tid < 160) ((f32x4*)Qs)[tid - 128] = ((const f32x4*)(Q + (size_t)bzu * PP))[tid - 128];
    __syncthreads();

    // ---- phi row: hs(512) @ W4(512x128) + b4 -> Ps ----
    {
        const int g    = tid & 31;
        const int ks   = tid >> 5;
        const int kBeg = ks * 64;
        const float* Wp = W4 + (size_t)kBeg * PP + g * 4;
        f32x4 acc = {0.f, 0.f, 0.f, 0.f};
        #pragma unroll 8
        for (int k = 0; k < 64; ++k) {
            const f32x4 w = *(const f32x4*)(Wp + (size_t)k * PP);
            const float s = hs[kBeg + k];
            acc.x = fmaf(s, w.x, acc.x);
            acc.y = fmaf(s, w.y, acc.y);
            acc.z = fmaf(s, w.z, acc.z);
            acc.w = fmaf(s, w.w, acc.w);
        }
        red4[ks * 33 + g] = acc;
        __syncthreads();
        if (tid < 32) {
            f32x4 a = red4[tid];
            #pragma unroll
            for (int s2 = 1; s2 < 8; ++s2) {
                const f32x4 c = red4[s2 * 33 + tid];
                a.x += c.x; a.y += c.y; a.z += c.z; a.w += c.w;
            }
            const f32x4 bb = *(const f32x4*)(b4 + tid * 4);
            a.x += bb.x; a.y += bb.y; a.z += bb.z; a.w += bb.w;
            ((f32x4*)Ps)[tid] = a;
        }
        __syncthreads();
    }

    // ---- bilinear main loop ----
    const int j0 = (tid & 31) << 2;            // constant across iterations
    const f32x4 q = *(const f32x4*)(Qs + j0);
    const f32x4 p = *(const f32x4*)(Ps + j0);

    const f32x4* L4 = (const f32x4*)(Linv + (size_t)bzu * (PP * PP));
    float accM = 0.f, accS = 0.f;
    #pragma unroll
    for (int it = 0; it < 16; ++it) {
        const int f = it * 256 + tid;          // float4 index within the matrix
        const f32x4 L = L4[f];
        const float pi = Ps[f >> 5];           // LDS broadcast (32 lanes/addr)
        const float sm = L.x * q.x + L.y * q.y + L.z * q.z + L.w * q.w;
        const float sp = L.x * p.x + L.y * p.y + L.z * p.z + L.w * p.w;
        accM = fmaf(pi, sm, accM);
        accS = fmaf(pi, sp, accS);
    }

    for (int off = 32; off; off >>= 1) {
        accM += __shfl_down(accM, off, 64);
        accS += __shfl_down(accS, off, 64);
    }
    const int wid = tid >> 6;
    if ((tid & 63) == 0) { red[wid] = accM; red[4 + wid] = accS; }
    __syncthreads();
    if (tid == 0) {
        const float m = (red[0] + red[1]) + (red[2] + red[3]);
        const float s = (red[4] + red[5]) + (red[6] + red[7]);
        out_mu[bzu]  = m;
        out_cov[bzu] = expf(logSigEps[u]) * (1.f + s);
    }
}

extern "C" void kernel_launch(void* const* d_in, const int* in_sizes, int n_in,
                              void* d_out, int out_size, void* d_ws, size_t ws_size,
                              hipStream_t stream) {
    const float* x         = (const float*)d_in[0];
    const float* Linv      = (const float*)d_in[1];
    const float* Q         = (const float*)d_in[2];
    const float* W1        = (const float*)d_in[3];
    const float* b1        = (const float*)d_in[4];
    const float* W2        = (const float*)d_in[5];
    const float* b2        = (const float*)d_in[6];
    const float* W3        = (const float*)d_in[7];
    const float* b3        = (const float*)d_in[8];
    const float* W4        = (const float*)d_in[9];
    const float* b4        = (const float*)d_in[10];
    const float* logSigEps = (const float*)d_in[11];

    float* ws  = (float*)d_ws;
    float* h2  = ws;                 // 64*512
    float* h3  = ws + BB * HH;       // 64*512

    l12_kernel<<<dim3(4, BB), 256, 0, stream>>>(x, W1, b1, W2, b2, h2);
    l3_kernel <<<dim3(4, BB), 256, 0, stream>>>(h2, W3, b3, h3);

    float* out_mu  = (float*)d_out;          // (B,Z,U,1) = 4096 floats
    float* out_cov = out_mu + BB * ZZ * UU;  // (B,Z,U)   = 4096 floats

    bilinear_phi_kernel<<<BB * ZZ * UU, 256, 0, stream>>>(
        Linv, Q, h3, W4, b4, logSigEps, out_mu, out_cov);
}

// Round 7
// 60.207 us; speedup vs baseline: 2.0395x; 1.2531x over previous
//
#include <hip/hip_runtime.h>
#include <math.h>

#define BB 64
#define ZZ 8
#define UU 8
#define PP 128
#define XX 64
#define HH 512

typedef float f32x4 __attribute__((ext_vector_type(4)));
typedef float f32x2 __attribute__((ext_vector_type(2)));

__device__ __forceinline__ float elu(float v) {
    return v > 0.f ? v : (expf(v) - 1.f);
}

// ---------------------------------------------------------------------------
// One 128-col chunk of a GEMV layer: out[0..128) = act(hs @ W[:, c0+..] + bias).
// hs = full input row in LDS (K floats). 256 threads = 32 f32x4 column
// groups x 8 K-slices; red padded (33-stride) to kill the reduce conflict.
// `out` is pre-offset by the caller (may point to LDS or global).
// ---------------------------------------------------------------------------
template<int K, bool ELU>
__device__ __forceinline__ void chunk_gemv(
    const float* __restrict__ hs, const float* __restrict__ W,
    const float* __restrict__ biasC0, float* __restrict__ out,
    int N, int c0, int tid, f32x4* __restrict__ red) {
    constexpr int KPER = K / 8;
    const int g    = tid & 31;
    const int ks   = tid >> 5;
    const int kBeg = ks * KPER;
    const float* Wp = W + (size_t)kBeg * N + c0 + g * 4;

    f32x4 acc = {0.f, 0.f, 0.f, 0.f};
    #pragma unroll 8
    for (int k = 0; k < KPER; ++k) {
        const f32x4 w = *(const f32x4*)(Wp + (size_t)k * N);
        const float s = hs[kBeg + k];
        acc.x = fmaf(s, w.x, acc.x);
        acc.y = fmaf(s, w.y, acc.y);
        acc.z = fmaf(s, w.z, acc.z);
        acc.w = fmaf(s, w.w, acc.w);
    }
    red[ks * 33 + g] = acc;
    __syncthreads();

    if (tid < 32) {
        f32x4 a = red[tid];
        #pragma unroll
        for (int s2 = 1; s2 < 8; ++s2) {
            const f32x4 b = red[s2 * 33 + tid];
            a.x += b.x; a.y += b.y; a.z += b.z; a.w += b.w;
        }
        const f32x4 bb = *(const f32x4*)(biasC0 + tid * 4);
        a.x += bb.x; a.y += bb.y; a.z += bb.z; a.w += bb.w;
        if (ELU) { a.x = elu(a.x); a.y = elu(a.y); a.z = elu(a.z); a.w = elu(a.w); }
        *(f32x4*)(out + tid * 4) = a;
    }
    __syncthreads();
}

// ---------------------------------------------------------------------------
// Layers 1+2 fused: grid (4, 64). Each block recomputes the full h1 row
// (W1 is 128 KB, L2-shared -> ~free), then its 128-col chunk of h2.
// ---------------------------------------------------------------------------
__global__ __launch_bounds__(256) void l12_kernel(
    const float* __restrict__ x,
    const float* __restrict__ W1, const float* __restrict__ b1,
    const float* __restrict__ W2, const float* __restrict__ b2,
    float* __restrict__ h2buf) {
    __shared__ __align__(16) float xs[XX];
    __shared__ __align__(16) float hs[HH];
    __shared__ __align__(16) f32x4 red[8 * 33];

    const int tid = threadIdx.x;
    const int r   = blockIdx.y;
    const int c0  = blockIdx.x * 128;

    if (tid < XX) xs[tid] = x[(size_t)r * XX + tid];
    __syncthreads();

    {   // h1 full row: thread tid -> cols 2tid, 2tid+1
        const f32x2* W = (const f32x2*)W1;   // [XX][HH/2]
        f32x2 a0 = {0.f, 0.f}, a1 = {0.f, 0.f};
        #pragma unroll 8
        for (int k = 0; k < XX; k += 2) {
            const f32x2 w0 = W[(k + 0) * (HH / 2) + tid];
            const f32x2 w1 = W[(k + 1) * (HH / 2) + tid];
            const float s0 = xs[k + 0], s1 = xs[k + 1];
            a0.x = fmaf(s0, w0.x, a0.x); a0.y = fmaf(s0, w0.y, a0.y);
            a1.x = fmaf(s1, w1.x, a1.x); a1.y = fmaf(s1, w1.y, a1.y);
        }
        const f32x2 bb = ((const f32x2*)b1)[tid];
        hs[2 * tid + 0] = elu(a0.x + a1.x + bb.x);
        hs[2 * tid + 1] = elu(a0.y + a1.y + bb.y);
    }
    __syncthreads();

    chunk_gemv<HH, true>(hs, W2, b2 + c0, h2buf + (size_t)r * HH + c0, HH, c0, tid, red);
}

// ---------------------------------------------------------------------------
// Layer 3 + partial-phi: grid (4, 64). Block (c,r) stages the h2 row,
// computes h3 cols [c*128,(c+1)*128) into LDS (never hits global), then
// the partial GEMV  pphi[c][r][:] = h3_chunk @ W4[c*128:(c+1)*128, :].
// Per-block W4 read = 64 KB -> 16 MB aggregate (vs 1 GB when fused into
// the 4096-block bilinear kernel -- the Round-6 L2 saturation mistake).
// ---------------------------------------------------------------------------
__global__ __launch_bounds__(256) void l34_kernel(
    const float* __restrict__ h2buf,
    const float* __restrict__ W3, const float* __restrict__ b3,
    const float* __restrict__ W4,
    float* __restrict__ pphi) {
    __shared__ __align__(16) float hs[HH];
    __shared__ __align__(16) float hs3[128];
    __shared__ __align__(16) f32x4 red[8 * 33];
    __shared__ float red2[2][128];

    const int tid = threadIdx.x;
    const int r   = blockIdx.y;
    const int c   = blockIdx.x;
    const int c0  = c * 128;

    ((f32x2*)hs)[tid] = ((const f32x2*)(h2buf + (size_t)r * HH))[tid];
    __syncthreads();

    chunk_gemv<HH, true>(hs, W3, b3 + c0, hs3, HH, c0, tid, red);
    // chunk_gemv ends with __syncthreads -> hs3 visible to all threads

    // partial phi: 2 k-slices x 128 cols
    {
        const int j    = tid & 127;
        const int half = tid >> 7;
        const int kBeg = half * 64;
        const float* Wp = W4 + (size_t)(c0 + kBeg) * PP + j;
        float acc = 0.f;
        #pragma unroll 8
        for (int k = 0; k < 64; ++k)
            acc = fmaf(hs3[kBeg + k], Wp[(size_t)k * PP], acc);
        red2[half][j] = acc;
    }
    __syncthreads();
    if (tid < 128)
        pphi[((size_t)c * BB + r) * PP + tid] = red2[0][tid] + red2[1][tid];
}

// ---------------------------------------------------------------------------
// Bilinear over Linv (128x128 fp32 per (b,z,u)):
//   mu  = sum_{i,j} phi[i] * L[i,j] * Qv[j]
//   cov = exp(logSigEps[u]) * (1 + sum_{i,j} phi[i] * L[i,j] * phi[j])
// Prologue: Ps = b4 + sum_c pphi[c][b]  (4 x 512 B -> negligible).
// Main loop: 16 coalesced f32x4 loads/thread; q/p fragments hoisted to
// registers (iteration-invariant); phi[i] via LDS broadcast.
// ---------------------------------------------------------------------------
__global__ __launch_bounds__(256) void bilinear_kernel(
    const float* __restrict__ Linv, const float* __restrict__ Q,
    const float* __restrict__ pphi, const float* __restrict__ b4,
    const float* __restrict__ logSigEps,
    float* __restrict__ out_mu, float* __restrict__ out_cov) {
    __shared__ __align__(16) float Ps[PP];
    __shared__ __align__(16) float Qs[PP];
    __shared__ float red[8];

    const int bzu = blockIdx.x;        // b*64 + z*8 + u
    const int b   = bzu >> 6;
    const int u   = bzu & 7;
    const int tid = threadIdx.x;

    if (tid < 128) {
        Ps[tid] = b4[tid]
                + pphi[((size_t)0 * BB + b) * PP + tid]
                + pphi[((size_t)1 * BB + b) * PP + tid]
                + pphi[((size_t)2 * BB + b) * PP + tid]
                + pphi[((size_t)3 * BB + b) * PP + tid];
    } else if (tid < 160) {
        ((f32x4*)Qs)[tid - 128] = ((const f32x4*)(Q + (size_t)bzu * PP))[tid - 128];
    }
    __syncthreads();

    const int j0 = (tid & 31) << 2;            // constant across iterations
    const f32x4 q = *(const f32x4*)(Qs + j0);
    const f32x4 p = *(const f32x4*)(Ps + j0);

    const f32x4* L4 = (const f32x4*)(Linv + (size_t)bzu * (PP * PP));
    float accM = 0.f, accS = 0.f;
    #pragma unroll
    for (int it = 0; it < 16; ++it) {
        const int f = it * 256 + tid;          // float4 index within the matrix
        const f32x4 L = L4[f];
        const float pi = Ps[f >> 5];           // LDS broadcast (32 lanes/addr)
        const float sm = L.x * q.x + L.y * q.y + L.z * q.z + L.w * q.w;
        const float sp = L.x * p.x + L.y * p.y + L.z * p.z + L.w * p.w;
        accM = fmaf(pi, sm, accM);
        accS = fmaf(pi, sp, accS);
    }

    for (int off = 32; off; off >>= 1) {
        accM += __shfl_down(accM, off, 64);
        accS += __shfl_down(accS, off, 64);
    }
    const int wid = tid >> 6;
    if ((tid & 63) == 0) { red[wid] = accM; red[4 + wid] = accS; }
    __syncthreads();
    if (tid == 0) {
        const float m = (red[0] + red[1]) + (red[2] + red[3]);
        const float s = (red[4] + red[5]) + (red[6] + red[7]);
        out_mu[bzu]  = m;
        out_cov[bzu] = expf(logSigEps[u]) * (1.f + s);
    }
}

extern "C" void kernel_launch(void* const* d_in, const int* in_sizes, int n_in,
                              void* d_out, int out_size, void* d_ws, size_t ws_size,
                              hipStream_t stream) {
    const float* x         = (const float*)d_in[0];
    const float* Linv      = (const float*)d_in[1];
    const float* Q         = (const float*)d_in[2];
    const float* W1        = (const float*)d_in[3];
    const float* b1        = (const float*)d_in[4];
    const float* W2        = (const float*)d_in[5];
    const float* b2        = (const float*)d_in[6];
    const float* W3        = (const float*)d_in[7];
    const float* b3        = (const float*)d_in[8];
    const float* W4        = (const float*)d_in[9];
    const float* b4        = (const float*)d_in[10];
    const float* logSigEps = (const float*)d_in[11];

    float* ws   = (float*)d_ws;
    float* h2   = ws;                 // 64*512
    float* pphi = ws + BB * HH;       // 4*64*128

    l12_kernel<<<dim3(4, BB), 256, 0, stream>>>(x, W1, b1, W2, b2, h2);
    l34_kernel<<<dim3(4, BB), 256, 0, stream>>>(h2, W3, b3, W4, pphi);

    float* out_mu  = (float*)d_out;          // (B,Z,U,1) = 4096 floats
    float* out_cov = out_mu + BB * ZZ * UU;  // (B,Z,U)   = 4096 floats

    bilinear_kernel<<<BB * ZZ * UU, 256, 0, stream>>>(
        Linv, Q, pphi, b4, logSigEps, out_mu, out_cov);
}

// Round 8
// 58.314 us; speedup vs baseline: 2.1057x; 1.0325x over previous
//
#include <hip/hip_runtime.h>
#include <math.h>

#define BB 64
#define ZZ 8
#define UU 8
#define PP 128
#define XX 64
#define HH 512

typedef float f32x4 __attribute__((ext_vector_type(4)));
typedef float f32x2 __attribute__((ext_vector_type(2)));

__device__ __forceinline__ float elu(float v) {
    return v > 0.f ? v : (expf(v) - 1.f);
}

// ---------------------------------------------------------------------------
// One 128-col chunk of a GEMV layer: out[0..128) = act(hs @ W[:, c0+..] + bias).
// hs = full input row in LDS (K floats). 256 threads = 32 f32x4 column
// groups x 8 K-slices; red padded (33-stride) to kill the reduce conflict.
// ---------------------------------------------------------------------------
template<int K, bool ELU>
__device__ __forceinline__ void chunk_gemv(
    const float* __restrict__ hs, const float* __restrict__ W,
    const float* __restrict__ biasC0, float* __restrict__ out,
    int N, int c0, int tid, f32x4* __restrict__ red) {
    constexpr int KPER = K / 8;
    const int g    = tid & 31;
    const int ks   = tid >> 5;
    const int kBeg = ks * KPER;
    const float* Wp = W + (size_t)kBeg * N + c0 + g * 4;

    f32x4 acc = {0.f, 0.f, 0.f, 0.f};
    #pragma unroll 8
    for (int k = 0; k < KPER; ++k) {
        const f32x4 w = *(const f32x4*)(Wp + (size_t)k * N);
        const float s = hs[kBeg + k];
        acc.x = fmaf(s, w.x, acc.x);
        acc.y = fmaf(s, w.y, acc.y);
        acc.z = fmaf(s, w.z, acc.z);
        acc.w = fmaf(s, w.w, acc.w);
    }
    red[ks * 33 + g] = acc;
    __syncthreads();

    if (tid < 32) {
        f32x4 a = red[tid];
        #pragma unroll
        for (int s2 = 1; s2 < 8; ++s2) {
            const f32x4 b = red[s2 * 33 + tid];
            a.x += b.x; a.y += b.y; a.z += b.z; a.w += b.w;
        }
        const f32x4 bb = *(const f32x4*)(biasC0 + tid * 4);
        a.x += bb.x; a.y += bb.y; a.z += bb.z; a.w += bb.w;
        if (ELU) { a.x = elu(a.x); a.y = elu(a.y); a.z = elu(a.z); a.w = elu(a.w); }
        *(f32x4*)(out + tid * 4) = a;
    }
    __syncthreads();
}

// ---------------------------------------------------------------------------
// Layers 1+2 fused: grid (4, 64). Each block recomputes the full h1 row
// (W1 is 128 KB, L2-shared -> ~free), then its 128-col chunk of h2.
// ---------------------------------------------------------------------------
__global__ __launch_bounds__(256) void l12_kernel(
    const float* __restrict__ x,
    const float* __restrict__ W1, const float* __restrict__ b1,
    const float* __restrict__ W2, const float* __restrict__ b2,
    float* __restrict__ h2buf) {
    __shared__ __align__(16) float xs[XX];
    __shared__ __align__(16) float hs[HH];
    __shared__ __align__(16) f32x4 red[8 * 33];

    const int tid = threadIdx.x;
    const int r   = blockIdx.y;
    const int c0  = blockIdx.x * 128;

    if (tid < XX) xs[tid] = x[(size_t)r * XX + tid];
    __syncthreads();

    {   // h1 full row: thread tid -> cols 2tid, 2tid+1
        const f32x2* W = (const f32x2*)W1;   // [XX][HH/2]
        f32x2 a0 = {0.f, 0.f}, a1 = {0.f, 0.f};
        #pragma unroll 8
        for (int k = 0; k < XX; k += 2) {
            const f32x2 w0 = W[(k + 0) * (HH / 2) + tid];
            const f32x2 w1 = W[(k + 1) * (HH / 2) + tid];
            const float s0 = xs[k + 0], s1 = xs[k + 1];
            a0.x = fmaf(s0, w0.x, a0.x); a0.y = fmaf(s0, w0.y, a0.y);
            a1.x = fmaf(s1, w1.x, a1.x); a1.y = fmaf(s1, w1.y, a1.y);
        }
        const f32x2 bb = ((const f32x2*)b1)[tid];
        hs[2 * tid + 0] = elu(a0.x + a1.x + bb.x);
        hs[2 * tid + 1] = elu(a0.y + a1.y + bb.y);
    }
    __syncthreads();

    chunk_gemv<HH, true>(hs, W2, b2 + c0, h2buf + (size_t)r * HH + c0, HH, c0, tid, red);
}

// ---------------------------------------------------------------------------
// Layer 3 + partial-phi: grid (4, 64). Block (c,r) stages the h2 row,
// computes h3 cols [c*128,(c+1)*128) into LDS (never hits global), then
// pphi[c][r][:] = h3_chunk @ W4[c*128:(c+1)*128, :]  (64 KB of W4/block).
// ---------------------------------------------------------------------------
__global__ __launch_bounds__(256) void l34_kernel(
    const float* __restrict__ h2buf,
    const float* __restrict__ W3, const float* __restrict__ b3,
    const float* __restrict__ W4,
    float* __restrict__ pphi) {
    __shared__ __align__(16) float hs[HH];
    __shared__ __align__(16) float hs3[128];
    __shared__ __align__(16) f32x4 red[8 * 33];
    __shared__ float red2[2][128];

    const int tid = threadIdx.x;
    const int r   = blockIdx.y;
    const int c   = blockIdx.x;
    const int c0  = c * 128;

    ((f32x2*)hs)[tid] = ((const f32x2*)(h2buf + (size_t)r * HH))[tid];
    __syncthreads();

    chunk_gemv<HH, true>(hs, W3, b3 + c0, hs3, HH, c0, tid, red);

    {   // partial phi: 2 k-slices x 128 cols
        const int j    = tid & 127;
        const int half = tid >> 7;
        const int kBeg = half * 64;
        const float* Wp = W4 + (size_t)(c0 + kBeg) * PP + j;
        float acc = 0.f;
        #pragma unroll 8
        for (int k = 0; k < 64; ++k)
            acc = fmaf(hs3[kBeg + k], Wp[(size_t)k * PP], acc);
        red2[half][j] = acc;
    }
    __syncthreads();
    if (tid < 128)
        pphi[((size_t)c * BB + r) * PP + tid] = red2[0][tid] + red2[1][tid];
}

// ---------------------------------------------------------------------------
// Bilinear over Linv. TWO consecutive (b,z,u) per block (same b -> shared
// phi prologue, halved per-block fixed cost, 32 loads in flight/thread).
// Nontemporal loads: Linv has zero reuse -- skip L2 insertion.
//   mu  = sum_{i,j} phi[i] * L[i,j] * Qv[j]
//   cov = exp(logSigEps[u]) * (1 + sum_{i,j} phi[i] * L[i,j] * phi[j])
// ---------------------------------------------------------------------------
__global__ __launch_bounds__(256) void bilinear_kernel(
    const float* __restrict__ Linv, const float* __restrict__ Q,
    const float* __restrict__ pphi, const float* __restrict__ b4,
    const float* __restrict__ logSigEps,
    float* __restrict__ out_mu, float* __restrict__ out_cov) {
    __shared__ __align__(16) float Ps[PP];
    __shared__ __align__(16) float Qs0[PP];
    __shared__ __align__(16) float Qs1[PP];
    __shared__ float red[16];

    const int bzu0 = blockIdx.x * 2;   // both matrices share b (64 % 2 == 0)
    const int bzu1 = bzu0 + 1;
    const int b    = bzu0 >> 6;
    const int tid  = threadIdx.x;

    if (tid < 128) {
        Ps[tid] = b4[tid]
                + pphi[((size_t)0 * BB + b) * PP + tid]
                + pphi[((size_t)1 * BB + b) * PP + tid]
                + pphi[((size_t)2 * BB + b) * PP + tid]
                + pphi[((size_t)3 * BB + b) * PP + tid];
    } else if (tid < 160) {
        ((f32x4*)Qs0)[tid - 128] = ((const f32x4*)(Q + (size_t)bzu0 * PP))[tid - 128];
    } else if (tid < 192) {
        ((f32x4*)Qs1)[tid - 160] = ((const f32x4*)(Q + (size_t)bzu1 * PP))[tid - 160];
    }
    __syncthreads();

    const int j0 = (tid & 31) << 2;            // constant across iterations
    const f32x4 q0 = *(const f32x4*)(Qs0 + j0);
    const f32x4 q1 = *(const f32x4*)(Qs1 + j0);
    const f32x4 p  = *(const f32x4*)(Ps + j0);

    const f32x4* LA = (const f32x4*)(Linv + (size_t)bzu0 * (PP * PP));
    const f32x4* LB = (const f32x4*)(Linv + (size_t)bzu1 * (PP * PP));
    float accM0 = 0.f, accS0 = 0.f, accM1 = 0.f, accS1 = 0.f;
    #pragma unroll
    for (int it = 0; it < 16; ++it) {
        const int f = it * 256 + tid;          // float4 index within a matrix
        const f32x4 La = __builtin_nontemporal_load(LA + f);
        const f32x4 Lb = __builtin_nontemporal_load(LB + f);
        const float pi = Ps[f >> 5];           // LDS broadcast (32 lanes/addr)
        const float sm0 = La.x * q0.x + La.y * q0.y + La.z * q0.z + La.w * q0.w;
        const float sp0 = La.x * p.x  + La.y * p.y  + La.z * p.z  + La.w * p.w;
        const float sm1 = Lb.x * q1.x + Lb.y * q1.y + Lb.z * q1.z + Lb.w * q1.w;
        const float sp1 = Lb.x * p.x  + Lb.y * p.y  + Lb.z * p.z  + Lb.w * p.w;
        accM0 = fmaf(pi, sm0, accM0);
        accS0 = fmaf(pi, sp0, accS0);
        accM1 = fmaf(pi, sm1, accM1);
        accS1 = fmaf(pi, sp1, accS1);
    }

    for (int off = 32; off; off >>= 1) {
        accM0 += __shfl_down(accM0, off, 64);
        accS0 += __shfl_down(accS0, off, 64);
        accM1 += __shfl_down(accM1, off, 64);
        accS1 += __shfl_down(accS1, off, 64);
    }
    const int wid = tid >> 6;
    if ((tid & 63) == 0) {
        red[wid]      = accM0; red[4 + wid]  = accS0;
        red[8 + wid]  = accM1; red[12 + wid] = accS1;
    }
    __syncthreads();
    if (tid == 0) {
        const float m0 = (red[0] + red[1]) + (red[2] + red[3]);
        const float s0 = (red[4] + red[5]) + (red[6] + red[7]);
        const float m1 = (red[8] + red[9]) + (red[10] + red[11]);
        const float s1 = (red[12] + red[13]) + (red[14] + red[15]);
        out_mu[bzu0]  = m0;
        out_cov[bzu0] = expf(logSigEps[bzu0 & 7]) * (1.f + s0);
        out_mu[bzu1]  = m1;
        out_cov[bzu1] = expf(logSigEps[bzu1 & 7]) * (1.f + s1);
    }
}

extern "C" void kernel_launch(void* const* d_in, const int* in_sizes, int n_in,
                              void* d_out, int out_size, void* d_ws, size_t ws_size,
                              hipStream_t stream) {
    const float* x         = (const float*)d_in[0];
    const float* Linv      = (const float*)d_in[1];
    const float* Q         = (const float*)d_in[2];
    const float* W1        = (const float*)d_in[3];
    const float* b1        = (const float*)d_in[4];
    const float* W2        = (const float*)d_in[5];
    const float* b2        = (const float*)d_in[6];
    const float* W3        = (const float*)d_in[7];
    const float* b3        = (const float*)d_in[8];
    const float* W4        = (const float*)d_in[9];
    const float* b4        = (const float*)d_in[10];
    const float* logSigEps = (const float*)d_in[11];

    float* ws   = (float*)d_ws;
    float* h2   = ws;                 // 64*512
    float* pphi = ws + BB * HH;       // 4*64*128

    l12_kernel<<<dim3(4, BB), 256, 0, stream>>>(x, W1, b1, W2, b2, h2);
    l34_kernel<<<dim3(4, BB), 256, 0, stream>>>(h2, W3, b3, W4, pphi);

    float* out_mu  = (float*)d_out;          // (B,Z,U,1) = 4096 floats
    float* out_cov = out_mu + BB * ZZ * UU;  // (B,Z,U)   = 4096 floats

    bilinear_kernel<<<(BB * ZZ * UU) / 2, 256, 0, stream>>>(
        Linv, Q, pphi, b4, logSigEps, out_mu, out_cov);
}